// Round 1
// baseline (610.983 us; speedup 1.0000x reference)
//
#include <hip/hip_runtime.h>
#include <hip/hip_bf16.h>

// Problem: x[4,2048,1024] f32; w_qkv[1024,3072]; w_out[1024,1024]; b_out[1024]
// out[4,2048,1024] f32.  HEADS=16, DH=64, scale=0.125.

typedef __attribute__((ext_vector_type(4))) float f32x4;
typedef __attribute__((ext_vector_type(8))) unsigned short u16x8;
typedef __attribute__((ext_vector_type(4))) unsigned short u16x4;
typedef __attribute__((ext_vector_type(8))) __bf16 bf16x8;

static __device__ __forceinline__ f32x4 mfma_bf16(u16x8 a, u16x8 b, f32x4 c) {
    return __builtin_amdgcn_mfma_f32_16x16x32_bf16(
        __builtin_bit_cast(bf16x8, a), __builtin_bit_cast(bf16x8, b), c, 0, 0, 0);
}

static __device__ __forceinline__ unsigned short f2bf(float f) {
    unsigned int u = __builtin_bit_cast(unsigned int, f);
    u += 0x7fffu + ((u >> 16) & 1u);   // RNE
    return (unsigned short)(u >> 16);
}

// ---------------- convert x (f32 -> bf16), vectorized ----------------
__global__ void k_cvt(const float* __restrict__ in, unsigned short* __restrict__ out, int n4) {
    int i = blockIdx.x * blockDim.x + threadIdx.x;
    int stride = gridDim.x * blockDim.x;
    for (; i < n4; i += stride) {
        f32x4 v = ((const f32x4*)in)[i];
        u16x4 o;
        #pragma unroll
        for (int j = 0; j < 4; ++j) o[j] = f2bf(v[j]);
        ((u16x4*)out)[i] = o;
    }
}

// ---------------- transpose f32 [R][C] -> bf16 [C][R] ----------------
__global__ void k_transpose(const float* __restrict__ in, unsigned short* __restrict__ out,
                            int R, int C) {
    __shared__ float tile[32][33];
    int c0 = blockIdx.x * 32, r0 = blockIdx.y * 32;
    int tx = threadIdx.x, ty = threadIdx.y;   // block (32,8)
    #pragma unroll
    for (int i = ty; i < 32; i += 8)
        tile[i][tx] = in[(size_t)(r0 + i) * C + c0 + tx];
    __syncthreads();
    #pragma unroll
    for (int i = ty; i < 32; i += 8)
        out[(size_t)(c0 + i) * R + r0 + tx] = f2bf(tile[tx][i]);
}

// ---------------- GEMM: A[8192][1024]bf16 @ BT[N][1024]bf16 ----------------
// mode 0: epilogue scatters to Q(x0.125)/K/VT bf16 head-major buffers (N=3072)
// mode 1: epilogue writes f32 out + bias (N=1024)
__global__ __launch_bounds__(256) void k_gemm(
    const unsigned short* __restrict__ A,
    const unsigned short* __restrict__ BT,
    const float* __restrict__ bias,
    float* __restrict__ outf,
    unsigned short* __restrict__ Qs,
    unsigned short* __restrict__ Ks,
    unsigned short* __restrict__ VTs,
    int mode)
{
    __shared__ unsigned short As[128 * 32];
    __shared__ unsigned short Bs[128 * 32];
    const int K = 1024;
    const int tid = threadIdx.x, lane = tid & 63, wave = tid >> 6;
    const int m0 = blockIdx.y * 128, n0 = blockIdx.x * 128;
    const int wm = (wave >> 1) * 64, wn = (wave & 1) * 64;
    const int lr = lane & 15, half = lane >> 4;

    f32x4 acc[4][4] = {};

    for (int k0 = 0; k0 < K; k0 += 32) {
        #pragma unroll
        for (int ch = 0; ch < 2; ++ch) {
            int c = tid + ch * 256;
            int row = c >> 2, slot = c & 3;
            int sw = (slot ^ ((row >> 1) & 3));
            u16x8 va = *(const u16x8*)&A[(size_t)(m0 + row) * K + k0 + slot * 8];
            *(u16x8*)&As[row * 32 + sw * 8] = va;
            u16x8 vb = *(const u16x8*)&BT[(size_t)(n0 + row) * K + k0 + slot * 8];
            *(u16x8*)&Bs[row * 32 + sw * 8] = vb;
        }
        __syncthreads();
        u16x8 af[4], bfr[4];
        #pragma unroll
        for (int i = 0; i < 4; ++i) {
            int ra = wm + i * 16 + lr;
            af[i] = *(const u16x8*)&As[ra * 32 + ((half ^ ((ra >> 1) & 3)) * 8)];
            int rb = wn + i * 16 + lr;
            bfr[i] = *(const u16x8*)&Bs[rb * 32 + ((half ^ ((rb >> 1) & 3)) * 8)];
        }
        #pragma unroll
        for (int i = 0; i < 4; ++i)
            #pragma unroll
            for (int j = 0; j < 4; ++j)
                acc[i][j] = mfma_bf16(af[i], bfr[j], acc[i][j]);
        __syncthreads();
    }

    // epilogue: C[row][col], row=(l>>4)*4+r within 16-frag, col=l&15
    #pragma unroll
    for (int i = 0; i < 4; ++i) {
        #pragma unroll
        for (int j = 0; j < 4; ++j) {
            #pragma unroll
            for (int r = 0; r < 4; ++r) {
                int row = m0 + wm + i * 16 + half * 4 + r;   // token 0..8191
                int col = n0 + wn + j * 16 + lr;             // 0..N-1
                float v = acc[i][j][r];
                if (mode == 1) {
                    outf[(size_t)row * 1024 + col] = v + bias[col];
                } else {
                    int part = col >> 10, cj = col & 1023;
                    int h = cj >> 6, d = cj & 63;
                    int b = row >> 11, n = row & 2047;
                    int bh = b * 16 + h;
                    if (part == 0)
                        Qs[((size_t)bh * 2048 + n) * 64 + d] = f2bf(v * 0.125f);
                    else if (part == 1)
                        Ks[((size_t)bh * 2048 + n) * 64 + d] = f2bf(v);
                    else
                        VTs[((size_t)bh * 64 + d) * 2048 + n] = f2bf(v);
                }
            }
        }
    }
}

// ---------------- flash attention ----------------
// grid (2048/64, 64): blockIdx.y = bh, block 256 = 4 waves x 16 Q-rows.
// Q pre-scaled by 0.125. K[bh][2048][64], VT[bh][64][2048] bf16.
__global__ __launch_bounds__(256) void k_attn(
    const unsigned short* __restrict__ Qs,
    const unsigned short* __restrict__ Ks,
    const unsigned short* __restrict__ VTs,
    unsigned short* __restrict__ attn)   // [8192][1024] bf16
{
    __shared__ unsigned short Pt[4][16 * 64];   // per-wave P tile [16 q][64 j], swizzled
    const int tid = threadIdx.x, lane = tid & 63, wave = tid >> 6;
    const int bh = blockIdx.y;
    const int qr0 = blockIdx.x * 64 + wave * 16;
    const int lr = lane & 15, half = lane >> 4;

    const unsigned short* Qbase = Qs + ((size_t)bh * 2048 + qr0) * 64;
    const unsigned short* Kbase = Ks + (size_t)bh * 2048 * 64;
    const unsigned short* Vbase = VTs + (size_t)bh * 64 * 2048;

    u16x8 aq[2];
    #pragma unroll
    for (int s = 0; s < 2; ++s)
        aq[s] = *(const u16x8*)&Qbase[lr * 64 + s * 32 + half * 8];

    float m[4], lsum[4];
    f32x4 o[4] = {};
    #pragma unroll
    for (int r = 0; r < 4; ++r) { m[r] = -1e30f; lsum[r] = 0.f; }
    unsigned short* P = Pt[wave];

    for (int j0 = 0; j0 < 2048; j0 += 64) {
        f32x4 sacc[4] = {};
        #pragma unroll
        for (int c = 0; c < 4; ++c) {
            #pragma unroll
            for (int s = 0; s < 2; ++s) {
                u16x8 bk = *(const u16x8*)&Kbase[(size_t)(j0 + c * 16 + lr) * 64 + s * 32 + half * 8];
                sacc[c] = mfma_bf16(aq[s], bk, sacc[c]);
            }
        }
        // row max over 64 cols: 4 frags in-lane, then across 16 lanes of the group
        float t[4];
        #pragma unroll
        for (int r = 0; r < 4; ++r)
            t[r] = fmaxf(fmaxf(sacc[0][r], sacc[1][r]), fmaxf(sacc[2][r], sacc[3][r]));
        #pragma unroll
        for (int mask = 1; mask <= 8; mask <<= 1)
            #pragma unroll
            for (int r = 0; r < 4; ++r)
                t[r] = fmaxf(t[r], __shfl_xor(t[r], mask, 64));

        float mn[4], sf[4];
        #pragma unroll
        for (int r = 0; r < 4; ++r) {
            mn[r] = fmaxf(m[r], t[r]);
            sf[r] = __expf(m[r] - mn[r]);
            m[r] = mn[r];
        }
        float rs[4] = {0.f, 0.f, 0.f, 0.f};
        #pragma unroll
        for (int c = 0; c < 4; ++c) {
            #pragma unroll
            for (int r = 0; r < 4; ++r) {
                float p = __expf(sacc[c][r] - mn[r]);
                rs[r] += p;
                int row = half * 4 + r;          // q row in tile
                int col = c * 16 + lr;           // j in tile
                int slot = ((col * 2) >> 4) ^ (row & 7);
                P[row * 64 + slot * 8 + (lr & 7)] = f2bf(p);
            }
        }
        #pragma unroll
        for (int mask = 1; mask <= 8; mask <<= 1)
            #pragma unroll
            for (int r = 0; r < 4; ++r)
                rs[r] += __shfl_xor(rs[r], mask, 64);
        #pragma unroll
        for (int r = 0; r < 4; ++r) lsum[r] = lsum[r] * sf[r] + rs[r];
        #pragma unroll
        for (int c = 0; c < 4; ++c)
            #pragma unroll
            for (int r = 0; r < 4; ++r)
                o[c][r] *= sf[r];
        // PV: A = P[16 q][64 j] from LDS, B = VT fragments (contiguous along j)
        #pragma unroll
        for (int s = 0; s < 2; ++s) {
            int slot = (s * 4 + half) ^ (lr & 7);
            u16x8 ap = *(const u16x8*)&P[lr * 64 + slot * 8];
            #pragma unroll
            for (int c = 0; c < 4; ++c) {
                u16x8 bv = *(const u16x8*)&Vbase[(size_t)(c * 16 + lr) * 2048 + j0 + s * 32 + half * 8];
                o[c] = mfma_bf16(ap, bv, o[c]);
            }
        }
    }

    int b = bh >> 4, h = bh & 15;
    #pragma unroll
    for (int c = 0; c < 4; ++c) {
        #pragma unroll
        for (int r = 0; r < 4; ++r) {
            int row = b * 2048 + qr0 + half * 4 + r;
            int col = h * 64 + c * 16 + lr;
            attn[(size_t)row * 1024 + col] = f2bf(o[c][r] / lsum[r]);
        }
    }
}

extern "C" void kernel_launch(void* const* d_in, const int* in_sizes, int n_in,
                              void* d_out, int out_size, void* d_ws, size_t ws_size,
                              hipStream_t stream) {
    const float* x     = (const float*)d_in[0];
    const float* w_qkv = (const float*)d_in[1];
    const float* w_out = (const float*)d_in[2];
    const float* b_out = (const float*)d_in[3];
    float* out = (float*)d_out;

    char* ws = (char*)d_ws;
    size_t off = 0;
    auto alloc = [&](size_t bytes) -> void* {
        void* p = ws + off;
        off += (bytes + 255) & ~(size_t)255;
        return p;
    };
    unsigned short* xb    = (unsigned short*)alloc(8192ull * 1024 * 2);
    unsigned short* wqkvT = (unsigned short*)alloc(3072ull * 1024 * 2);
    unsigned short* woutT = (unsigned short*)alloc(1024ull * 1024 * 2);
    unsigned short* Qs    = (unsigned short*)alloc(64ull * 2048 * 64 * 2);
    unsigned short* Ks    = (unsigned short*)alloc(64ull * 2048 * 64 * 2);
    unsigned short* VTs   = (unsigned short*)alloc(64ull * 2048 * 64 * 2);
    unsigned short* attn  = (unsigned short*)alloc(8192ull * 1024 * 2);
    if (off > ws_size) return;   // insufficient scratch -> visible clean failure

    k_cvt<<<2048, 256, 0, stream>>>(x, xb, 8192 * 1024 / 4);
    k_transpose<<<dim3(3072 / 32, 1024 / 32), dim3(32, 8), 0, stream>>>(w_qkv, wqkvT, 1024, 3072);
    k_transpose<<<dim3(1024 / 32, 1024 / 32), dim3(32, 8), 0, stream>>>(w_out, woutT, 1024, 1024);
    k_gemm<<<dim3(3072 / 128, 8192 / 128), 256, 0, stream>>>(xb, wqkvT, nullptr, nullptr, Qs, Ks, VTs, 0);
    k_attn<<<dim3(2048 / 64, 64), 256, 0, stream>>>(Qs, Ks, VTs, attn);
    k_gemm<<<dim3(1024 / 128, 8192 / 128), 256, 0, stream>>>(attn, woutT, b_out, out, nullptr, nullptr, nullptr, 1);
}

// Round 2
// 293.821 us; speedup vs baseline: 2.0794x; 2.0794x over previous
//
#include <hip/hip_runtime.h>
#include <hip/hip_bf16.h>

// Problem: x[4,2048,1024] f32; w_qkv[1024,3072]; w_out[1024,1024]; b_out[1024]
// out[4,2048,1024] f32.  HEADS=16, DH=64, scale=0.125.

typedef __attribute__((ext_vector_type(4))) float f32x4;
typedef __attribute__((ext_vector_type(16))) float f32x16;
typedef __attribute__((ext_vector_type(8))) unsigned short u16x8;
typedef __attribute__((ext_vector_type(4))) unsigned short u16x4;
typedef __attribute__((ext_vector_type(4))) unsigned int u32x4;
typedef __attribute__((ext_vector_type(8))) __bf16 bf16x8;

static __device__ __forceinline__ f32x4 mfma_bf16(u16x8 a, u16x8 b, f32x4 c) {
    return __builtin_amdgcn_mfma_f32_16x16x32_bf16(
        __builtin_bit_cast(bf16x8, a), __builtin_bit_cast(bf16x8, b), c, 0, 0, 0);
}
static __device__ __forceinline__ f32x16 mfma32(u16x8 a, u16x8 b, f32x16 c) {
    return __builtin_amdgcn_mfma_f32_32x32x16_bf16(
        __builtin_bit_cast(bf16x8, a), __builtin_bit_cast(bf16x8, b), c, 0, 0, 0);
}

static __device__ __forceinline__ unsigned short f2bf(float f) {
    unsigned int u = __builtin_bit_cast(unsigned int, f);
    u += 0x7fffu + ((u >> 16) & 1u);   // RNE
    return (unsigned short)(u >> 16);
}
static __device__ __forceinline__ unsigned int cvt_pk_bf16(float a, float b) {
    unsigned int r;
    asm("v_cvt_pk_bf16_f32 %0, %1, %2" : "=v"(r) : "v"(a), "v"(b));
    return r;
}
typedef const __attribute__((address_space(1))) unsigned int* gp1_t;
typedef __attribute__((address_space(3))) unsigned int* lp3_t;
static __device__ __forceinline__ void gl_lds16(const void* g, void* l) {
    __builtin_amdgcn_global_load_lds((gp1_t)g, (lp3_t)l, 16, 0, 0);
}

// ---------------- convert x (f32 -> bf16), vectorized ----------------
__global__ void k_cvt(const float* __restrict__ in, unsigned short* __restrict__ out, int n4) {
    int i = blockIdx.x * blockDim.x + threadIdx.x;
    int stride = gridDim.x * blockDim.x;
    for (; i < n4; i += stride) {
        f32x4 v = ((const f32x4*)in)[i];
        u16x4 o;
        #pragma unroll
        for (int j = 0; j < 4; ++j) o[j] = f2bf(v[j]);
        ((u16x4*)out)[i] = o;
    }
}

// ---------------- transpose f32 [R][C] -> bf16 [C][R] ----------------
__global__ void k_transpose(const float* __restrict__ in, unsigned short* __restrict__ out,
                            int R, int C) {
    __shared__ float tile[32][33];
    int c0 = blockIdx.x * 32, r0 = blockIdx.y * 32;
    int tx = threadIdx.x, ty = threadIdx.y;   // block (32,8)
    #pragma unroll
    for (int i = ty; i < 32; i += 8)
        tile[i][tx] = in[(size_t)(r0 + i) * C + c0 + tx];
    __syncthreads();
    #pragma unroll
    for (int i = ty; i < 32; i += 8)
        out[(size_t)(c0 + i) * R + r0 + tx] = f2bf(tile[tx][i]);
}

// ---------------- GEMM: A[8192][1024]bf16 @ BT[N][1024]bf16 ----------------
__global__ __launch_bounds__(256) void k_gemm(
    const unsigned short* __restrict__ A,
    const unsigned short* __restrict__ BT,
    const float* __restrict__ bias,
    float* __restrict__ outf,
    unsigned short* __restrict__ Qs,
    unsigned short* __restrict__ Ks,
    unsigned short* __restrict__ VTs,
    int mode)
{
    __shared__ unsigned short As[128 * 32];
    __shared__ unsigned short Bs[128 * 32];
    const int K = 1024;
    const int tid = threadIdx.x, lane = tid & 63, wave = tid >> 6;
    const int m0 = blockIdx.y * 128, n0 = blockIdx.x * 128;
    const int wm = (wave >> 1) * 64, wn = (wave & 1) * 64;
    const int lr = lane & 15, half = lane >> 4;

    f32x4 acc[4][4] = {};

    for (int k0 = 0; k0 < K; k0 += 32) {
        #pragma unroll
        for (int ch = 0; ch < 2; ++ch) {
            int c = tid + ch * 256;
            int row = c >> 2, slot = c & 3;
            int sw = (slot ^ ((row >> 1) & 3));
            u16x8 va = *(const u16x8*)&A[(size_t)(m0 + row) * K + k0 + slot * 8];
            *(u16x8*)&As[row * 32 + sw * 8] = va;
            u16x8 vb = *(const u16x8*)&BT[(size_t)(n0 + row) * K + k0 + slot * 8];
            *(u16x8*)&Bs[row * 32 + sw * 8] = vb;
        }
        __syncthreads();
        u16x8 af[4], bfr[4];
        #pragma unroll
        for (int i = 0; i < 4; ++i) {
            int ra = wm + i * 16 + lr;
            af[i] = *(const u16x8*)&As[ra * 32 + ((half ^ ((ra >> 1) & 3)) * 8)];
            int rb = wn + i * 16 + lr;
            bfr[i] = *(const u16x8*)&Bs[rb * 32 + ((half ^ ((rb >> 1) & 3)) * 8)];
        }
        #pragma unroll
        for (int i = 0; i < 4; ++i)
            #pragma unroll
            for (int j = 0; j < 4; ++j)
                acc[i][j] = mfma_bf16(af[i], bfr[j], acc[i][j]);
        __syncthreads();
    }

    #pragma unroll
    for (int i = 0; i < 4; ++i) {
        #pragma unroll
        for (int j = 0; j < 4; ++j) {
            #pragma unroll
            for (int r = 0; r < 4; ++r) {
                int row = m0 + wm + i * 16 + half * 4 + r;
                int col = n0 + wn + j * 16 + lr;
                float v = acc[i][j][r];
                if (mode == 1) {
                    outf[(size_t)row * 1024 + col] = v + bias[col];
                } else {
                    int part = col >> 10, cj = col & 1023;
                    int h = cj >> 6, d = cj & 63;
                    int b = row >> 11, n = row & 2047;
                    int bh = b * 16 + h;
                    if (part == 0)
                        Qs[((size_t)bh * 2048 + n) * 64 + d] = f2bf(v * 0.125f);
                    else if (part == 1)
                        Ks[((size_t)bh * 2048 + n) * 64 + d] = f2bf(v);
                    else
                        VTs[((size_t)bh * 64 + d) * 2048 + n] = f2bf(v);
                }
            }
        }
    }
}

// ---------------- flash attention, swapped-QK 32x32 structure ----------------
// grid (16, 64): blockIdx.y = bh; block 256 = 4 waves, each owns 32 q-rows.
// Per kv-tile (64 j): S^T = K·Q^T via mfma32 (lane holds 32 scores for ONE q),
// in-register softmax, cvt_pk+shfl_xor(32) P->A-frags, PV from VT LDS tile.
__global__ __launch_bounds__(256) void k_attn(
    const unsigned short* __restrict__ Qs,
    const unsigned short* __restrict__ Ks,
    const unsigned short* __restrict__ VTs,
    unsigned short* __restrict__ attn)   // [8192][1024] bf16
{
    __shared__ unsigned short Kt[2][64 * 64];   // [j][d], XOR-swizzled rows
    __shared__ unsigned short Vt[2][64 * 64];   // [d][j], XOR-swizzled rows
    const int tid = threadIdx.x, lane = tid & 63, wave = tid >> 6;
    const int bh = blockIdx.y;
    const int q0 = blockIdx.x * 128 + wave * 32;
    const int lq = lane & 31;
    const int hi = lane >> 5;
    const bool hib = hi != 0;

    const unsigned short* Kbase = Ks + (size_t)bh * 2048 * 64;
    const unsigned short* Vbase = VTs + (size_t)bh * 64 * 2048;

    // Q B-frags (persistent): lane provides Q[q0+lq][kk*16 + hi*8 + e]
    u16x8 qf[4];
    {
        const unsigned short* Qrow = Qs + ((size_t)bh * 2048 + q0 + lq) * 64;
        #pragma unroll
        for (int kk = 0; kk < 4; ++kk)
            qf[kk] = *(const u16x8*)&Qrow[kk * 16 + hi * 8];
    }

    // staging: 8 chunks of 8 rows; wave stages chunks wave*2, wave*2+1.
    // LDS linear dest; source col pre-swizzled so LDS[row][slot s] = src col (s^(row&7)).
    const int srow = (lane >> 3);      // 0..7 within chunk
    const int sslot = lane & 7;
    auto stage = [&](int buf, int j0) {
        #pragma unroll
        for (int c = 0; c < 2; ++c) {
            int chunk = wave * 2 + c;
            int row = chunk * 8 + srow;
            int sw = (sslot ^ (row & 7)) * 8;
            gl_lds16(Kbase + (size_t)(j0 + row) * 64 + sw, &Kt[buf][chunk * 512]);
            gl_lds16(Vbase + (size_t)row * 2048 + j0 + sw, &Vt[buf][chunk * 512]);
        }
    };

    f32x16 o[2] = {};
    float m_run = -1e30f, lsum = 0.f;

    stage(0, 0);
    __syncthreads();
    int cur = 0;

    for (int t = 0; t < 32; ++t) {
        if (t < 31) stage(cur ^ 1, (t + 1) * 64);

        // ---- QK^T: S^T[j][q], 2 j-blocks of 32 ----
        f32x16 sacc[2] = {};
        __builtin_amdgcn_s_setprio(1);
        #pragma unroll
        for (int jb = 0; jb < 2; ++jb) {
            #pragma unroll
            for (int kk = 0; kk < 4; ++kk) {
                int row = jb * 32 + lq;
                u16x8 kf = *(const u16x8*)&Kt[cur][row * 64 + (((kk * 2 + hi) ^ (row & 7)) * 8)];
                sacc[jb] = mfma32(kf, qf[kk], sacc[jb]);
            }
        }
        __builtin_amdgcn_s_setprio(0);

        // ---- softmax (lane-local + one cross-half reduce) ----
        float mx[16];
        #pragma unroll
        for (int r = 0; r < 16; ++r) mx[r] = fmaxf(sacc[0][r], sacc[1][r]);
        #pragma unroll
        for (int s2 = 8; s2 >= 1; s2 >>= 1)
            #pragma unroll
            for (int r = 0; r < s2; ++r) mx[r] = fmaxf(mx[r], mx[r + s2]);
        float pmax = fmaxf(mx[0], __shfl_xor(mx[0], 32));

        if (!__all(pmax <= m_run + 8.0f)) {      // T13 defer-max
            float mnew = fmaxf(m_run, pmax);
            float sf = __expf(m_run - mnew);
            m_run = mnew;
            lsum *= sf;
            #pragma unroll
            for (int r = 0; r < 16; ++r) {
                int qrow = (r & 3) + 8 * (r >> 2) + 4 * hi;
                float sfr = __shfl(sf, qrow);
                o[0][r] *= sfr;
                o[1][r] *= sfr;
            }
        }

        float sm[16];
        #pragma unroll
        for (int r = 0; r < 16; ++r) {
            float p0 = __expf(sacc[0][r] - m_run);
            float p1 = __expf(sacc[1][r] - m_run);
            sacc[0][r] = p0; sacc[1][r] = p1;
            sm[r] = p0 + p1;
        }
        #pragma unroll
        for (int s2 = 8; s2 >= 1; s2 >>= 1)
            #pragma unroll
            for (int r = 0; r < s2; ++r) sm[r] += sm[r + s2];
        lsum += sm[0] + __shfl_xor(sm[0], 32);

        // ---- T12: pack P to bf16 pairs, exchange halves ----
        unsigned int pk[2][8], sw[2][8];
        #pragma unroll
        for (int jb = 0; jb < 2; ++jb)
            #pragma unroll
            for (int i = 0; i < 8; ++i)
                pk[jb][i] = cvt_pk_bf16(sacc[jb][2 * i], sacc[jb][2 * i + 1]);
        #pragma unroll
        for (int jb = 0; jb < 2; ++jb)
            #pragma unroll
            for (int i = 0; i < 8; ++i)
                sw[jb][i] = __shfl_xor(pk[jb][i], 32);

        // ---- PV: O[q][d] += P · V ----
        __builtin_amdgcn_s_setprio(1);
        #pragma unroll
        for (int kk = 0; kk < 4; ++kk) {
            int jb = kk >> 1, base = (kk & 1) * 4;
            u32x4 paw;
            paw[0] = hib ? sw[jb][base + 2] : pk[jb][base + 0];
            paw[1] = hib ? sw[jb][base + 3] : pk[jb][base + 1];
            paw[2] = hib ? pk[jb][base + 2] : sw[jb][base + 0];
            paw[3] = hib ? pk[jb][base + 3] : sw[jb][base + 1];
            u16x8 pa = __builtin_bit_cast(u16x8, paw);
            #pragma unroll
            for (int db = 0; db < 2; ++db) {
                int row = db * 32 + lq;
                u16x8 vf = *(const u16x8*)&Vt[cur][row * 64 + (((kk * 2 + hi) ^ (row & 7)) * 8)];
                o[db] = mfma32(pa, vf, o[db]);
            }
        }
        __builtin_amdgcn_s_setprio(0);

        __syncthreads();   // drains vmcnt (stage) + lgkmcnt; next iter flips buffers
        cur ^= 1;
    }

    // ---- epilogue: divide by lsum (per O-row via shfl) and store ----
    int b = bh >> 4, h = bh & 15;
    float inv = 1.0f / lsum;
    #pragma unroll
    for (int r = 0; r < 16; ++r) {
        int qrow = (r & 3) + 8 * (r >> 2) + 4 * hi;
        float invr = __shfl(inv, qrow);
        size_t rowoff = (size_t)(b * 2048 + q0 + qrow) * 1024 + h * 64;
        attn[rowoff + lq]      = f2bf(o[0][r] * invr);
        attn[rowoff + 32 + lq] = f2bf(o[1][r] * invr);
    }
}

extern "C" void kernel_launch(void* const* d_in, const int* in_sizes, int n_in,
                              void* d_out, int out_size, void* d_ws, size_t ws_size,
                              hipStream_t stream) {
    const float* x     = (const float*)d_in[0];
    const float* w_qkv = (const float*)d_in[1];
    const float* w_out = (const float*)d_in[2];
    const float* b_out = (const float*)d_in[3];
    float* out = (float*)d_out;

    char* ws = (char*)d_ws;
    size_t off = 0;
    auto alloc = [&](size_t bytes) -> void* {
        void* p = ws + off;
        off += (bytes + 255) & ~(size_t)255;
        return p;
    };
    unsigned short* xb    = (unsigned short*)alloc(8192ull * 1024 * 2);
    unsigned short* wqkvT = (unsigned short*)alloc(3072ull * 1024 * 2);
    unsigned short* woutT = (unsigned short*)alloc(1024ull * 1024 * 2);
    unsigned short* Qs    = (unsigned short*)alloc(64ull * 2048 * 64 * 2);
    unsigned short* Ks    = (unsigned short*)alloc(64ull * 2048 * 64 * 2);
    unsigned short* VTs   = (unsigned short*)alloc(64ull * 2048 * 64 * 2);
    unsigned short* attn  = (unsigned short*)alloc(8192ull * 1024 * 2);
    if (off > ws_size) return;

    k_cvt<<<2048, 256, 0, stream>>>(x, xb, 8192 * 1024 / 4);
    k_transpose<<<dim3(3072 / 32, 1024 / 32), dim3(32, 8), 0, stream>>>(w_qkv, wqkvT, 1024, 3072);
    k_transpose<<<dim3(1024 / 32, 1024 / 32), dim3(32, 8), 0, stream>>>(w_out, woutT, 1024, 1024);
    k_gemm<<<dim3(3072 / 128, 8192 / 128), 256, 0, stream>>>(xb, wqkvT, nullptr, nullptr, Qs, Ks, VTs, 0);
    k_attn<<<dim3(16, 64), 256, 0, stream>>>(Qs, Ks, VTs, attn);
    k_gemm<<<dim3(1024 / 128, 8192 / 128), 256, 0, stream>>>(attn, woutT, b_out, out, nullptr, nullptr, nullptr, 1);
}

// Round 3
// 249.806 us; speedup vs baseline: 2.4458x; 1.1762x over previous
//
#include <hip/hip_runtime.h>
#include <hip/hip_bf16.h>

// Problem: x[4,2048,1024] f32; w_qkv[1024,3072]; w_out[1024,1024]; b_out[1024]
// out[4,2048,1024] f32.  HEADS=16, DH=64, scale=0.125 (folded with log2e into Q).

typedef __attribute__((ext_vector_type(4))) float f32x4;
typedef __attribute__((ext_vector_type(16))) float f32x16;
typedef __attribute__((ext_vector_type(8))) unsigned short u16x8;
typedef __attribute__((ext_vector_type(4))) unsigned short u16x4;
typedef __attribute__((ext_vector_type(4))) unsigned int u32x4;
typedef __attribute__((ext_vector_type(8))) __bf16 bf16x8;

static __device__ __forceinline__ f32x4 mfma_bf16(u16x8 a, u16x8 b, f32x4 c) {
    return __builtin_amdgcn_mfma_f32_16x16x32_bf16(
        __builtin_bit_cast(bf16x8, a), __builtin_bit_cast(bf16x8, b), c, 0, 0, 0);
}
static __device__ __forceinline__ f32x16 mfma32(u16x8 a, u16x8 b, f32x16 c) {
    return __builtin_amdgcn_mfma_f32_32x32x16_bf16(
        __builtin_bit_cast(bf16x8, a), __builtin_bit_cast(bf16x8, b), c, 0, 0, 0);
}

static __device__ __forceinline__ unsigned short f2bf(float f) {
    unsigned int u = __builtin_bit_cast(unsigned int, f);
    u += 0x7fffu + ((u >> 16) & 1u);   // RNE
    return (unsigned short)(u >> 16);
}
static __device__ __forceinline__ unsigned int cvt_pk_bf16(float a, float b) {
    unsigned int r;
    asm("v_cvt_pk_bf16_f32 %0, %1, %2" : "=v"(r) : "v"(a), "v"(b));
    return r;
}
static __device__ __forceinline__ float fexp2(float x) {   // D = 2^S0
    float r;
    asm("v_exp_f32 %0, %1" : "=v"(r) : "v"(x));
    return r;
}
static __device__ __forceinline__ float frcp(float x) {
    float r;
    asm("v_rcp_f32 %0, %1" : "=v"(r) : "v"(x));
    return r;
}
typedef const __attribute__((address_space(1))) unsigned int* gp1_t;
typedef __attribute__((address_space(3))) unsigned int* lp3_t;
static __device__ __forceinline__ void gl_lds16(const void* g, void* l) {
    __builtin_amdgcn_global_load_lds((gp1_t)g, (lp3_t)l, 16, 0, 0);
}

// ---------------- convert x (f32 -> bf16), vectorized ----------------
__global__ void k_cvt(const float* __restrict__ in, unsigned short* __restrict__ out, int n4) {
    int i = blockIdx.x * blockDim.x + threadIdx.x;
    int stride = gridDim.x * blockDim.x;
    for (; i < n4; i += stride) {
        f32x4 v = ((const f32x4*)in)[i];
        u16x4 o;
        #pragma unroll
        for (int j = 0; j < 4; ++j) o[j] = f2bf(v[j]);
        ((u16x4*)out)[i] = o;
    }
}

// ---------------- transpose f32 [R][C] -> bf16 [C][R] ----------------
__global__ void k_transpose(const float* __restrict__ in, unsigned short* __restrict__ out,
                            int R, int C) {
    __shared__ float tile[32][33];
    int c0 = blockIdx.x * 32, r0 = blockIdx.y * 32;
    int tx = threadIdx.x, ty = threadIdx.y;   // block (32,8)
    #pragma unroll
    for (int i = ty; i < 32; i += 8)
        tile[i][tx] = in[(size_t)(r0 + i) * C + c0 + tx];
    __syncthreads();
    #pragma unroll
    for (int i = ty; i < 32; i += 8)
        out[(size_t)(c0 + i) * R + r0 + tx] = f2bf(tile[tx][i]);
}

// ---------------- GEMM: A[8192][1024]bf16 @ BT[N][1024]bf16 ----------------
// Staging via global_load_lds width-16 (linear LDS dest, pre-swizzled source).
__global__ __launch_bounds__(256) void k_gemm(
    const unsigned short* __restrict__ A,
    const unsigned short* __restrict__ BT,
    const float* __restrict__ bias,
    float* __restrict__ outf,
    unsigned short* __restrict__ Qs,
    unsigned short* __restrict__ Ks,
    unsigned short* __restrict__ VTs,
    int mode)
{
    __shared__ unsigned short As[128 * 32];
    __shared__ unsigned short Bs[128 * 32];
    const int K = 1024;
    const int tid = threadIdx.x, lane = tid & 63, wave = tid >> 6;
    const int m0 = blockIdx.y * 128, n0 = blockIdx.x * 128;
    const int wm = (wave >> 1) * 64, wn = (wave & 1) * 64;
    const int lr = lane & 15, half = lane >> 4;

    // staging: chunk = 1024B = 16 rows x 32 shorts; wave owns chunks wave*2, wave*2+1
    const int crow = lane >> 2, cslot = lane & 3;

    f32x4 acc[4][4] = {};

    for (int k0 = 0; k0 < K; k0 += 32) {
        #pragma unroll
        for (int c = 0; c < 2; ++c) {
            int chunk = wave * 2 + c;
            int row = chunk * 16 + crow;
            int sw = (cslot ^ ((row >> 1) & 3)) * 8;
            gl_lds16(&A[(size_t)(m0 + row) * K + k0 + sw], &As[chunk * 512]);
            gl_lds16(&BT[(size_t)(n0 + row) * K + k0 + sw], &Bs[chunk * 512]);
        }
        __syncthreads();
        u16x8 af[4], bfr[4];
        #pragma unroll
        for (int i = 0; i < 4; ++i) {
            int ra = wm + i * 16 + lr;
            af[i] = *(const u16x8*)&As[ra * 32 + ((half ^ ((ra >> 1) & 3)) * 8)];
            int rb = wn + i * 16 + lr;
            bfr[i] = *(const u16x8*)&Bs[rb * 32 + ((half ^ ((rb >> 1) & 3)) * 8)];
        }
        #pragma unroll
        for (int i = 0; i < 4; ++i)
            #pragma unroll
            for (int j = 0; j < 4; ++j)
                acc[i][j] = mfma_bf16(af[i], bfr[j], acc[i][j]);
        __syncthreads();
    }

    #pragma unroll
    for (int i = 0; i < 4; ++i) {
        #pragma unroll
        for (int j = 0; j < 4; ++j) {
            #pragma unroll
            for (int r = 0; r < 4; ++r) {
                int row = m0 + wm + i * 16 + half * 4 + r;
                int col = n0 + wn + j * 16 + lr;
                float v = acc[i][j][r];
                if (mode == 1) {
                    outf[(size_t)row * 1024 + col] = v + bias[col];
                } else {
                    int part = col >> 10, cj = col & 1023;
                    int h = cj >> 6, d = cj & 63;
                    int b = row >> 11, n = row & 2047;
                    int bh = b * 16 + h;
                    if (part == 0)   // fold 0.125 * log2(e) so attn can use 2^s directly
                        Qs[((size_t)bh * 2048 + n) * 64 + d] = f2bf(v * 0.18033688f);
                    else if (part == 1)
                        Ks[((size_t)bh * 2048 + n) * 64 + d] = f2bf(v);
                    else
                        VTs[((size_t)bh * 64 + d) * 2048 + n] = f2bf(v);
                }
            }
        }
    }
}

// ---------------- flash attention, swapped-QK 32x32, no-max exp2 softmax ----
// grid (16, 64): blockIdx.y = bh; block 256 = 4 waves, each owns 32 q-rows.
// Scores are in log2 units (scale folded into Q): p = 2^s, normalize at end.
// Row sums computed by MFMA against a ones-fragment (osum rows == o rows).
__global__ __launch_bounds__(256) void k_attn(
    const unsigned short* __restrict__ Qs,
    const unsigned short* __restrict__ Ks,
    const unsigned short* __restrict__ VTs,
    unsigned short* __restrict__ attn)   // [8192][1024] bf16
{
    __shared__ unsigned short Kt[2][64 * 64];   // [j][d], XOR-swizzled 16B slots
    __shared__ unsigned short Vt[2][64 * 64];   // [d][j], XOR-swizzled 16B slots
    const int tid = threadIdx.x, lane = tid & 63, wave = tid >> 6;
    const int bh = blockIdx.y;
    const int q0 = blockIdx.x * 128 + wave * 32;
    const int lq = lane & 31;
    const int hi = lane >> 5;
    const bool hib = hi != 0;

    const unsigned short* Kbase = Ks + (size_t)bh * 2048 * 64;
    const unsigned short* Vbase = VTs + (size_t)bh * 64 * 2048;

    u16x8 qf[4];
    {
        const unsigned short* Qrow = Qs + ((size_t)bh * 2048 + q0 + lq) * 64;
        #pragma unroll
        for (int kk = 0; kk < 4; ++kk)
            qf[kk] = *(const u16x8*)&Qrow[kk * 16 + hi * 8];
    }

    const int srow = (lane >> 3);
    const int sslot = lane & 7;
    auto stage = [&](int buf, int j0) {
        #pragma unroll
        for (int c = 0; c < 2; ++c) {
            int chunk = wave * 2 + c;
            int row = chunk * 8 + srow;
            int sw = (sslot ^ (row & 7)) * 8;
            gl_lds16(Kbase + (size_t)(j0 + row) * 64 + sw, &Kt[buf][chunk * 512]);
            gl_lds16(Vbase + (size_t)row * 2048 + j0 + sw, &Vt[buf][chunk * 512]);
        }
    };

    f32x16 o[2] = {};
    f32x16 osum = {};
    const u16x8 onesf = {0x3F80, 0x3F80, 0x3F80, 0x3F80, 0x3F80, 0x3F80, 0x3F80, 0x3F80};

    stage(0, 0);
    __syncthreads();
    int cur = 0;

    for (int t = 0; t < 32; ++t) {
        if (t < 31) stage(cur ^ 1, (t + 1) * 64);

        // ---- QK^T: S^T[j][q] in log2 units ----
        f32x16 sacc[2] = {};
        __builtin_amdgcn_s_setprio(1);
        #pragma unroll
        for (int jb = 0; jb < 2; ++jb) {
            #pragma unroll
            for (int kk = 0; kk < 4; ++kk) {
                int row = jb * 32 + lq;
                u16x8 kf = *(const u16x8*)&Kt[cur][row * 64 + (((kk * 2 + hi) ^ (row & 7)) * 8)];
                sacc[jb] = mfma32(kf, qf[kk], sacc[jb]);
            }
        }
        __builtin_amdgcn_s_setprio(0);

        // ---- softmax numerator: p = 2^s (no max, no subtraction) ----
        #pragma unroll
        for (int jb = 0; jb < 2; ++jb)
            #pragma unroll
            for (int r = 0; r < 16; ++r)
                sacc[jb][r] = fexp2(sacc[jb][r]);

        // ---- pack P to bf16 pairs, exchange halves ----
        unsigned int pk[2][8], sw[2][8];
        #pragma unroll
        for (int jb = 0; jb < 2; ++jb)
            #pragma unroll
            for (int i = 0; i < 8; ++i)
                pk[jb][i] = cvt_pk_bf16(sacc[jb][2 * i], sacc[jb][2 * i + 1]);
        #pragma unroll
        for (int jb = 0; jb < 2; ++jb)
            #pragma unroll
            for (int i = 0; i < 8; ++i)
                sw[jb][i] = __shfl_xor(pk[jb][i], 32);

        // ---- PV + MFMA row-sum ----
        __builtin_amdgcn_s_setprio(1);
        #pragma unroll
        for (int kk = 0; kk < 4; ++kk) {
            int jb = kk >> 1, base = (kk & 1) * 4;
            u32x4 paw;
            paw[0] = hib ? sw[jb][base + 2] : pk[jb][base + 0];
            paw[1] = hib ? sw[jb][base + 3] : pk[jb][base + 1];
            paw[2] = hib ? pk[jb][base + 2] : sw[jb][base + 0];
            paw[3] = hib ? pk[jb][base + 3] : sw[jb][base + 1];
            u16x8 pa = __builtin_bit_cast(u16x8, paw);
            osum = mfma32(pa, onesf, osum);
            #pragma unroll
            for (int db = 0; db < 2; ++db) {
                int row = db * 32 + lq;
                u16x8 vf = *(const u16x8*)&Vt[cur][row * 64 + (((kk * 2 + hi) ^ (row & 7)) * 8)];
                o[db] = mfma32(pa, vf, o[db]);
            }
        }
        __builtin_amdgcn_s_setprio(0);

        __syncthreads();
        cur ^= 1;
    }

    // ---- epilogue: normalize and store (osum rows match o rows) ----
    int b = bh >> 4, h = bh & 15;
    #pragma unroll
    for (int r = 0; r < 16; ++r) {
        int qrow = (r & 3) + 8 * (r >> 2) + 4 * hi;
        float invr = frcp(osum[r]);
        size_t rowoff = (size_t)(b * 2048 + q0 + qrow) * 1024 + h * 64;
        attn[rowoff + lq]      = f2bf(o[0][r] * invr);
        attn[rowoff + 32 + lq] = f2bf(o[1][r] * invr);
    }
}

extern "C" void kernel_launch(void* const* d_in, const int* in_sizes, int n_in,
                              void* d_out, int out_size, void* d_ws, size_t ws_size,
                              hipStream_t stream) {
    const float* x     = (const float*)d_in[0];
    const float* w_qkv = (const float*)d_in[1];
    const float* w_out = (const float*)d_in[2];
    const float* b_out = (const float*)d_in[3];
    float* out = (float*)d_out;

    char* ws = (char*)d_ws;
    size_t off = 0;
    auto alloc = [&](size_t bytes) -> void* {
        void* p = ws + off;
        off += (bytes + 255) & ~(size_t)255;
        return p;
    };
    unsigned short* xb    = (unsigned short*)alloc(8192ull * 1024 * 2);
    unsigned short* wqkvT = (unsigned short*)alloc(3072ull * 1024 * 2);
    unsigned short* woutT = (unsigned short*)alloc(1024ull * 1024 * 2);
    unsigned short* Qs    = (unsigned short*)alloc(64ull * 2048 * 64 * 2);
    unsigned short* Ks    = (unsigned short*)alloc(64ull * 2048 * 64 * 2);
    unsigned short* VTs   = (unsigned short*)alloc(64ull * 2048 * 64 * 2);
    unsigned short* attn  = (unsigned short*)alloc(8192ull * 1024 * 2);
    if (off > ws_size) return;

    k_cvt<<<2048, 256, 0, stream>>>(x, xb, 8192 * 1024 / 4);
    k_transpose<<<dim3(3072 / 32, 1024 / 32), dim3(32, 8), 0, stream>>>(w_qkv, wqkvT, 1024, 3072);
    k_transpose<<<dim3(1024 / 32, 1024 / 32), dim3(32, 8), 0, stream>>>(w_out, woutT, 1024, 1024);
    k_gemm<<<dim3(3072 / 128, 8192 / 128), 256, 0, stream>>>(xb, wqkvT, nullptr, nullptr, Qs, Ks, VTs, 0);
    k_attn<<<dim3(16, 64), 256, 0, stream>>>(Qs, Ks, VTs, attn);
    k_gemm<<<dim3(1024 / 128, 8192 / 128), 256, 0, stream>>>(attn, woutT, b_out, out, nullptr, nullptr, nullptr, 1);
}

// Round 4
// 228.674 us; speedup vs baseline: 2.6719x; 1.0924x over previous
//
#include <hip/hip_runtime.h>
#include <hip/hip_bf16.h>

// Problem: x[4,2048,1024] f32; w_qkv[1024,3072]; w_out[1024,1024]; b_out[1024]
// out[4,2048,1024] f32.  HEADS=16, DH=64, scale=0.125 (folded with log2e into Q).

typedef __attribute__((ext_vector_type(4))) float f32x4;
typedef __attribute__((ext_vector_type(16))) float f32x16;
typedef __attribute__((ext_vector_type(8))) unsigned short u16x8;
typedef __attribute__((ext_vector_type(4))) unsigned short u16x4;
typedef __attribute__((ext_vector_type(4))) unsigned int u32x4;
typedef __attribute__((ext_vector_type(8))) __bf16 bf16x8;

static __device__ __forceinline__ f32x4 mfma_bf16(u16x8 a, u16x8 b, f32x4 c) {
    return __builtin_amdgcn_mfma_f32_16x16x32_bf16(
        __builtin_bit_cast(bf16x8, a), __builtin_bit_cast(bf16x8, b), c, 0, 0, 0);
}
static __device__ __forceinline__ f32x16 mfma32(u16x8 a, u16x8 b, f32x16 c) {
    return __builtin_amdgcn_mfma_f32_32x32x16_bf16(
        __builtin_bit_cast(bf16x8, a), __builtin_bit_cast(bf16x8, b), c, 0, 0, 0);
}

static __device__ __forceinline__ unsigned short f2bf(float f) {
    unsigned int u = __builtin_bit_cast(unsigned int, f);
    u += 0x7fffu + ((u >> 16) & 1u);   // RNE
    return (unsigned short)(u >> 16);
}
static __device__ __forceinline__ unsigned int cvt_pk_bf16(float a, float b) {
    unsigned int r;
    asm("v_cvt_pk_bf16_f32 %0, %1, %2" : "=v"(r) : "v"(a), "v"(b));
    return r;
}
static __device__ __forceinline__ float fexp2(float x) {   // D = 2^S0
    float r;
    asm("v_exp_f32 %0, %1" : "=v"(r) : "v"(x));
    return r;
}
static __device__ __forceinline__ float frcp(float x) {
    float r;
    asm("v_rcp_f32 %0, %1" : "=v"(r) : "v"(x));
    return r;
}
typedef const __attribute__((address_space(1))) unsigned int* gp1_t;
typedef __attribute__((address_space(3))) unsigned int* lp3_t;
static __device__ __forceinline__ void gl_lds16(const void* g, void* l) {
    __builtin_amdgcn_global_load_lds((gp1_t)g, (lp3_t)l, 16, 0, 0);
}

// ---------------- convert x (f32 -> bf16), vectorized ----------------
__global__ void k_cvt(const float* __restrict__ in, unsigned short* __restrict__ out, int n4) {
    int i = blockIdx.x * blockDim.x + threadIdx.x;
    int stride = gridDim.x * blockDim.x;
    for (; i < n4; i += stride) {
        f32x4 v = ((const f32x4*)in)[i];
        u16x4 o;
        #pragma unroll
        for (int j = 0; j < 4; ++j) o[j] = f2bf(v[j]);
        ((u16x4*)out)[i] = o;
    }
}

// ---------------- transpose f32 [R][C] -> bf16 [C][R] ----------------
__global__ void k_transpose(const float* __restrict__ in, unsigned short* __restrict__ out,
                            int R, int C) {
    __shared__ float tile[32][33];
    int c0 = blockIdx.x * 32, r0 = blockIdx.y * 32;
    int tx = threadIdx.x, ty = threadIdx.y;   // block (32,8)
    #pragma unroll
    for (int i = ty; i < 32; i += 8)
        tile[i][tx] = in[(size_t)(r0 + i) * C + c0 + tx];
    __syncthreads();
    #pragma unroll
    for (int i = ty; i < 32; i += 8)
        out[(size_t)(c0 + i) * R + r0 + tx] = f2bf(tile[tx][i]);
}

// ---------------- GEMM: A[8192][1024]bf16 @ BT[N][1024]bf16 ----------------
__global__ __launch_bounds__(256) void k_gemm(
    const unsigned short* __restrict__ A,
    const unsigned short* __restrict__ BT,
    const float* __restrict__ bias,
    float* __restrict__ outf,
    unsigned short* __restrict__ Qs,
    unsigned short* __restrict__ Ks,
    unsigned short* __restrict__ VTs,
    int mode)
{
    __shared__ unsigned short As[128 * 32];
    __shared__ unsigned short Bs[128 * 32];
    const int K = 1024;
    const int tid = threadIdx.x, lane = tid & 63, wave = tid >> 6;
    const int m0 = blockIdx.y * 128, n0 = blockIdx.x * 128;
    const int wm = (wave >> 1) * 64, wn = (wave & 1) * 64;
    const int lr = lane & 15, half = lane >> 4;

    const int crow = lane >> 2, cslot = lane & 3;

    f32x4 acc[4][4] = {};

    for (int k0 = 0; k0 < K; k0 += 32) {
        #pragma unroll
        for (int c = 0; c < 2; ++c) {
            int chunk = wave * 2 + c;
            int row = chunk * 16 + crow;
            int sw = (cslot ^ ((row >> 1) & 3)) * 8;
            gl_lds16(&A[(size_t)(m0 + row) * K + k0 + sw], &As[chunk * 512]);
            gl_lds16(&BT[(size_t)(n0 + row) * K + k0 + sw], &Bs[chunk * 512]);
        }
        __syncthreads();
        u16x8 af[4], bfr[4];
        #pragma unroll
        for (int i = 0; i < 4; ++i) {
            int ra = wm + i * 16 + lr;
            af[i] = *(const u16x8*)&As[ra * 32 + ((half ^ ((ra >> 1) & 3)) * 8)];
            int rb = wn + i * 16 + lr;
            bfr[i] = *(const u16x8*)&Bs[rb * 32 + ((half ^ ((rb >> 1) & 3)) * 8)];
        }
        #pragma unroll
        for (int i = 0; i < 4; ++i)
            #pragma unroll
            for (int j = 0; j < 4; ++j)
                acc[i][j] = mfma_bf16(af[i], bfr[j], acc[i][j]);
        __syncthreads();
    }

    #pragma unroll
    for (int i = 0; i < 4; ++i) {
        #pragma unroll
        for (int j = 0; j < 4; ++j) {
            #pragma unroll
            for (int r = 0; r < 4; ++r) {
                int row = m0 + wm + i * 16 + half * 4 + r;
                int col = n0 + wn + j * 16 + lr;
                float v = acc[i][j][r];
                if (mode == 1) {
                    outf[(size_t)row * 1024 + col] = v + bias[col];
                } else {
                    int part = col >> 10, cj = col & 1023;
                    int h = cj >> 6, d = cj & 63;
                    int b = row >> 11, n = row & 2047;
                    int bh = b * 16 + h;
                    if (part == 0)   // fold 0.125 * log2(e): attn uses p = 2^s
                        Qs[((size_t)bh * 2048 + n) * 64 + d] = f2bf(v * 0.18033688f);
                    else if (part == 1)
                        Ks[((size_t)bh * 2048 + n) * 64 + d] = f2bf(v);
                    else
                        VTs[((size_t)bh * 64 + d) * 2048 + n] = f2bf(v);
                }
            }
        }
    }
}

// ---------------- flash attention: swapped-QK 32x32, 2 q-blocks/wave --------
// grid (8, 64) XCD-swizzled; block 256 = 4 waves; wave owns 64 q-rows (2x32).
// LDS tiles: 32 rows x 256B, 16-slot XOR swizzle (2-way max aliasing = free).
// p = 2^s directly (scale*log2e folded into Q); row sums via ones-MFMA.
__global__ __launch_bounds__(256, 2) void k_attn(
    const unsigned short* __restrict__ Qs,
    const unsigned short* __restrict__ Ks,
    const unsigned short* __restrict__ VTs,
    unsigned short* __restrict__ attn)   // [8192][1024] bf16
{
    __shared__ unsigned short Kt[2][64 * 64];
    __shared__ unsigned short Vt[2][64 * 64];
    const int tid = threadIdx.x, lane = tid & 63, wave = tid >> 6;

    // XCD swizzle: all 8 q-blocks of one bh land on the same XCD
    int lin = blockIdx.y * 8 + blockIdx.x;          // 512 wgs, 512%8==0 -> bijective
    int virt = (lin & 7) * 64 + (lin >> 3);
    int bh = virt >> 3;
    int q0 = (virt & 7) * 256 + wave * 64;

    const int lq = lane & 31;
    const int hi = lane >> 5;
    const bool hib = hi != 0;

    const unsigned short* Kbase = Ks + (size_t)bh * 2048 * 64;
    const unsigned short* Vbase = VTs + (size_t)bh * 64 * 2048;

    u16x8 qf0[4], qf1[4];
    {
        const unsigned short* Qr0 = Qs + ((size_t)bh * 2048 + q0 + lq) * 64;
        const unsigned short* Qr1 = Qr0 + 32 * 64;
        #pragma unroll
        for (int kk = 0; kk < 4; ++kk) {
            qf0[kk] = *(const u16x8*)&Qr0[kk * 16 + hi * 8];
            qf1[kk] = *(const u16x8*)&Qr1[kk * 16 + hi * 8];
        }
    }

    // stage: chunk = 1KB = 4 LDS-rows x 16 slots. lane l: row chunk*4+(l>>4),
    // slot l&15. src slot v = (l&15) ^ (row&15); high=v>>3, dslot=v&7.
    const int srow_in = lane >> 4, sslot = lane & 15;
    auto stage = [&](int buf, int j0) {
        #pragma unroll
        for (int c = 0; c < 2; ++c) {
            int chunk = wave * 2 + c;
            int row = chunk * 4 + srow_in;           // 0..31
            int v = sslot ^ (row & 15);
            int high = v >> 3, dsl = (v & 7) * 8;
            gl_lds16(Kbase + (size_t)(j0 + high * 32 + row) * 64 + dsl, &Kt[buf][chunk * 512]);
            gl_lds16(Vbase + (size_t)(high * 32 + row) * 2048 + j0 + dsl, &Vt[buf][chunk * 512]);
        }
    };

    f32x16 o0[2] = {}, o1[2] = {};
    f32x16 osum0 = {}, osum1 = {};
    const u16x8 onesf = {0x3F80, 0x3F80, 0x3F80, 0x3F80, 0x3F80, 0x3F80, 0x3F80, 0x3F80};

    stage(0, 0);
    __syncthreads();
    int cur = 0;

    for (int t = 0; t < 32; ++t) {
        if (t < 31) stage(cur ^ 1, (t + 1) * 64);

        // ---- QK^T: S^T[j][q] in log2 units, both q-blocks share kf ----
        f32x16 sacc0[2] = {}, sacc1[2] = {};
        __builtin_amdgcn_s_setprio(1);
        #pragma unroll
        for (int jb = 0; jb < 2; ++jb) {
            u16x8 kf[4];
            #pragma unroll
            for (int kk = 0; kk < 4; ++kk) {
                int s = (jb * 8 + kk * 2 + hi) ^ (lq & 15);
                kf[kk] = *(const u16x8*)&Kt[cur][lq * 128 + s * 8];
            }
            #pragma unroll
            for (int kk = 0; kk < 4; ++kk) sacc0[jb] = mfma32(kf[kk], qf0[kk], sacc0[jb]);
            #pragma unroll
            for (int kk = 0; kk < 4; ++kk) sacc1[jb] = mfma32(kf[kk], qf1[kk], sacc1[jb]);
        }
        __builtin_amdgcn_s_setprio(0);

        // ---- p = 2^s, pack to bf16 pairs ----
        unsigned int pk0[16], pk1[16];
        #pragma unroll
        for (int jb = 0; jb < 2; ++jb)
            #pragma unroll
            for (int i = 0; i < 8; ++i) {
                pk0[jb * 8 + i] = cvt_pk_bf16(fexp2(sacc0[jb][2 * i]), fexp2(sacc0[jb][2 * i + 1]));
                pk1[jb * 8 + i] = cvt_pk_bf16(fexp2(sacc1[jb][2 * i]), fexp2(sacc1[jb][2 * i + 1]));
            }

        // ---- PV + ones-MFMA row sums ----
        #pragma unroll
        for (int kk = 0; kk < 4; ++kk) {
            const int jb = kk >> 1, base = (kk >> 1) * 8 + (kk & 1) * 4;
            unsigned int a0 = pk0[base + 0], a1 = pk0[base + 1], a2 = pk0[base + 2], a3 = pk0[base + 3];
            unsigned int b0 = pk1[base + 0], b1 = pk1[base + 1], b2 = pk1[base + 2], b3 = pk1[base + 3];
            unsigned int sa0 = __shfl_xor(a0, 32), sa1 = __shfl_xor(a1, 32);
            unsigned int sa2 = __shfl_xor(a2, 32), sa3 = __shfl_xor(a3, 32);
            unsigned int sb0 = __shfl_xor(b0, 32), sb1 = __shfl_xor(b1, 32);
            unsigned int sb2 = __shfl_xor(b2, 32), sb3 = __shfl_xor(b3, 32);
            u32x4 w0, w1;
            w0[0] = hib ? sa2 : a0;  w0[1] = hib ? sa3 : a1;
            w0[2] = hib ? a2 : sa0;  w0[3] = hib ? a3 : sa1;
            w1[0] = hib ? sb2 : b0;  w1[1] = hib ? sb3 : b1;
            w1[2] = hib ? b2 : sb0;  w1[3] = hib ? b3 : sb1;
            u16x8 pa0 = __builtin_bit_cast(u16x8, w0);
            u16x8 pa1 = __builtin_bit_cast(u16x8, w1);
            __builtin_amdgcn_s_setprio(1);
            osum0 = mfma32(pa0, onesf, osum0);
            osum1 = mfma32(pa1, onesf, osum1);
            #pragma unroll
            for (int db = 0; db < 2; ++db) {
                int s = (db * 8 + kk * 2 + hi) ^ (lq & 15);
                u16x8 vf = *(const u16x8*)&Vt[cur][lq * 128 + s * 8];
                o0[db] = mfma32(pa0, vf, o0[db]);
                o1[db] = mfma32(pa1, vf, o1[db]);
            }
            __builtin_amdgcn_s_setprio(0);
        }

        __syncthreads();
        cur ^= 1;
    }

    // ---- epilogue: normalize and store ----
    int b = bh >> 4, h = bh & 15;
    #pragma unroll
    for (int r = 0; r < 16; ++r) {
        int qrow = (r & 3) + 8 * (r >> 2) + 4 * hi;
        float i0 = frcp(osum0[r]);
        float i1 = frcp(osum1[r]);
        size_t ro0 = (size_t)(b * 2048 + q0 + qrow) * 1024 + h * 64;
        size_t ro1 = (size_t)(b * 2048 + q0 + 32 + qrow) * 1024 + h * 64;
        attn[ro0 + lq]      = f2bf(o0[0][r] * i0);
        attn[ro0 + 32 + lq] = f2bf(o0[1][r] * i0);
        attn[ro1 + lq]      = f2bf(o1[0][r] * i1);
        attn[ro1 + 32 + lq] = f2bf(o1[1][r] * i1);
    }
}

extern "C" void kernel_launch(void* const* d_in, const int* in_sizes, int n_in,
                              void* d_out, int out_size, void* d_ws, size_t ws_size,
                              hipStream_t stream) {
    const float* x     = (const float*)d_in[0];
    const float* w_qkv = (const float*)d_in[1];
    const float* w_out = (const float*)d_in[2];
    const float* b_out = (const float*)d_in[3];
    float* out = (float*)d_out;

    char* ws = (char*)d_ws;
    size_t off = 0;
    auto alloc = [&](size_t bytes) -> void* {
        void* p = ws + off;
        off += (bytes + 255) & ~(size_t)255;
        return p;
    };
    unsigned short* xb    = (unsigned short*)alloc(8192ull * 1024 * 2);
    unsigned short* wqkvT = (unsigned short*)alloc(3072ull * 1024 * 2);
    unsigned short* woutT = (unsigned short*)alloc(1024ull * 1024 * 2);
    unsigned short* Qs    = (unsigned short*)alloc(64ull * 2048 * 64 * 2);
    unsigned short* Ks    = (unsigned short*)alloc(64ull * 2048 * 64 * 2);
    unsigned short* VTs   = (unsigned short*)alloc(64ull * 2048 * 64 * 2);
    unsigned short* attn  = (unsigned short*)alloc(8192ull * 1024 * 2);
    if (off > ws_size) return;

    k_cvt<<<2048, 256, 0, stream>>>(x, xb, 8192 * 1024 / 4);
    k_transpose<<<dim3(3072 / 32, 1024 / 32), dim3(32, 8), 0, stream>>>(w_qkv, wqkvT, 1024, 3072);
    k_transpose<<<dim3(1024 / 32, 1024 / 32), dim3(32, 8), 0, stream>>>(w_out, woutT, 1024, 1024);
    k_gemm<<<dim3(3072 / 128, 8192 / 128), 256, 0, stream>>>(xb, wqkvT, nullptr, nullptr, Qs, Ks, VTs, 0);
    k_attn<<<dim3(8, 64), 256, 0, stream>>>(Qs, Ks, VTs, attn);
    k_gemm<<<dim3(1024 / 128, 8192 / 128), 256, 0, stream>>>(attn, woutT, b_out, out, nullptr, nullptr, nullptr, 1);
}

// Round 5
// 224.277 us; speedup vs baseline: 2.7242x; 1.0196x over previous
//
#include <hip/hip_runtime.h>
#include <hip/hip_bf16.h>

// Problem: x[4,2048,1024] f32; w_qkv[1024,3072]; w_out[1024,1024]; b_out[1024]
// out[4,2048,1024] f32.  HEADS=16, DH=64, scale=0.125 (folded with log2e into Q).

typedef __attribute__((ext_vector_type(4))) float f32x4;
typedef __attribute__((ext_vector_type(16))) float f32x16;
typedef __attribute__((ext_vector_type(8))) unsigned short u16x8;
typedef __attribute__((ext_vector_type(4))) unsigned short u16x4;
typedef __attribute__((ext_vector_type(4))) unsigned int u32x4;
typedef __attribute__((ext_vector_type(8))) __bf16 bf16x8;

static __device__ __forceinline__ f32x4 mfma_bf16(u16x8 a, u16x8 b, f32x4 c) {
    return __builtin_amdgcn_mfma_f32_16x16x32_bf16(
        __builtin_bit_cast(bf16x8, a), __builtin_bit_cast(bf16x8, b), c, 0, 0, 0);
}
static __device__ __forceinline__ f32x16 mfma32(u16x8 a, u16x8 b, f32x16 c) {
    return __builtin_amdgcn_mfma_f32_32x32x16_bf16(
        __builtin_bit_cast(bf16x8, a), __builtin_bit_cast(bf16x8, b), c, 0, 0, 0);
}

static __device__ __forceinline__ unsigned short f2bf(float f) {
    unsigned int u = __builtin_bit_cast(unsigned int, f);
    u += 0x7fffu + ((u >> 16) & 1u);   // RNE
    return (unsigned short)(u >> 16);
}
static __device__ __forceinline__ unsigned int cvt_pk_bf16(float a, float b) {
    unsigned int r;
    asm("v_cvt_pk_bf16_f32 %0, %1, %2" : "=v"(r) : "v"(a), "v"(b));
    return r;
}
static __device__ __forceinline__ float fexp2(float x) {   // D = 2^S0
    float r;
    asm("v_exp_f32 %0, %1" : "=v"(r) : "v"(x));
    return r;
}
static __device__ __forceinline__ float frcp(float x) {
    float r;
    asm("v_rcp_f32 %0, %1" : "=v"(r) : "v"(x));
    return r;
}
typedef const __attribute__((address_space(1))) unsigned int* gp1_t;
typedef __attribute__((address_space(3))) unsigned int* lp3_t;
static __device__ __forceinline__ void gl_lds16(const void* g, void* l) {
    __builtin_amdgcn_global_load_lds((gp1_t)g, (lp3_t)l, 16, 0, 0);
}

// ---------------- convert x (f32 -> bf16), vectorized ----------------
__global__ void k_cvt(const float* __restrict__ in, unsigned short* __restrict__ out, int n4) {
    int i = blockIdx.x * blockDim.x + threadIdx.x;
    int stride = gridDim.x * blockDim.x;
    for (; i < n4; i += stride) {
        f32x4 v = ((const f32x4*)in)[i];
        u16x4 o;
        #pragma unroll
        for (int j = 0; j < 4; ++j) o[j] = f2bf(v[j]);
        ((u16x4*)out)[i] = o;
    }
}

// ---------------- transpose f32 [R][C] -> bf16 [C][R] ----------------
__global__ void k_transpose(const float* __restrict__ in, unsigned short* __restrict__ out,
                            int R, int C) {
    __shared__ float tile[32][33];
    int c0 = blockIdx.x * 32, r0 = blockIdx.y * 32;
    int tx = threadIdx.x, ty = threadIdx.y;   // block (32,8)
    #pragma unroll
    for (int i = ty; i < 32; i += 8)
        tile[i][tx] = in[(size_t)(r0 + i) * C + c0 + tx];
    __syncthreads();
    #pragma unroll
    for (int i = ty; i < 32; i += 8)
        out[(size_t)(c0 + i) * R + r0 + tx] = f2bf(tile[tx][i]);
}

// ---------------- GEMM: A[8192][1024]bf16 @ BT[N][1024]bf16 ----------------
// 256x128 tile, BK=64, 8 waves (4M x 2N, 64x64/wave), double-buffered LDS,
// counted-vmcnt schedule: stage(t+1) -> vmcnt(6) -> bar -> ds_read -> lgkm(0)
// -> bar -> 32 MFMA. Loads stay in flight across the MFMA phase (T4).
__global__ __launch_bounds__(512, 1) void k_gemm(
    const unsigned short* __restrict__ A,
    const unsigned short* __restrict__ BT,
    const float* __restrict__ bias,
    float* __restrict__ outf,
    unsigned short* __restrict__ Qs,
    unsigned short* __restrict__ Ks,
    unsigned short* __restrict__ VTs,
    int mode)
{
    __shared__ unsigned short As[2][256 * 64];
    __shared__ unsigned short Bs[2][128 * 64];
    const int K = 1024;
    const int tid = threadIdx.x, lane = tid & 63, wave = tid >> 6;

    // bijective XCD swizzle (nwg % 8 == 0 in both uses)
    int gx = gridDim.x;
    int nwg = gx * gridDim.y;
    int lin = blockIdx.y * gx + blockIdx.x;
    int virt = (lin & 7) * (nwg >> 3) + (lin >> 3);
    int bx = virt % gx, by = virt / gx;
    const int m0 = by * 256, n0 = bx * 128;

    const int wm = (wave >> 1) * 64, wn = (wave & 1) * 64;
    const int lr = lane & 15, half = lane >> 4;
    const int srow = lane >> 3, sslot = lane & 7;

    // stage K-tile t into buffer buf. Chunk = 1KB = 8 rows x 8 slots(16B).
    // LDS[row][s] holds global k-chunk (s ^ (row&7)) -> inverse-swizzled src.
    auto stage = [&](int buf, int t) {
        int k0 = t * 64;
        #pragma unroll
        for (int r = 0; r < 4; ++r) {
            int chunk = r * 8 + wave;
            int row = chunk * 8 + srow;
            int koff = (sslot ^ (row & 7)) * 8;
            gl_lds16(&A[(size_t)(m0 + row) * K + k0 + koff], &As[buf][chunk * 512]);
        }
        #pragma unroll
        for (int r = 0; r < 2; ++r) {
            int chunk = r * 8 + wave;
            int row = chunk * 8 + srow;
            int koff = (sslot ^ (row & 7)) * 8;
            gl_lds16(&BT[(size_t)(n0 + row) * K + k0 + koff], &Bs[buf][chunk * 512]);
        }
    };

    f32x4 acc[4][4] = {};

    stage(0, 0);
    for (int t = 0; t < 16; ++t) {
        if (t < 15) {
            stage((t + 1) & 1, t + 1);
            asm volatile("s_waitcnt vmcnt(6)" ::: "memory");   // tile t's 6 loads done
        } else {
            asm volatile("s_waitcnt vmcnt(0)" ::: "memory");
        }
        __builtin_amdgcn_sched_barrier(0);
        __builtin_amdgcn_s_barrier();

        const unsigned short* Ab = As[t & 1];
        const unsigned short* Bb = Bs[t & 1];
        u16x8 af[4][2], bfr[4][2];
        #pragma unroll
        for (int i = 0; i < 4; ++i)
            #pragma unroll
            for (int ks = 0; ks < 2; ++ks) {
                int ra = wm + i * 16 + lr;
                af[i][ks] = *(const u16x8*)&Ab[ra * 64 + (((ks * 4 + half) ^ (ra & 7)) * 8)];
                int rb = wn + i * 16 + lr;
                bfr[i][ks] = *(const u16x8*)&Bb[rb * 64 + (((ks * 4 + half) ^ (rb & 7)) * 8)];
            }
        asm volatile("s_waitcnt lgkmcnt(0)" ::: "memory");
        __builtin_amdgcn_sched_barrier(0);
        __builtin_amdgcn_s_barrier();   // all waves consumed buf -> next stage may overwrite

        __builtin_amdgcn_s_setprio(1);
        #pragma unroll
        for (int ks = 0; ks < 2; ++ks)
            #pragma unroll
            for (int i = 0; i < 4; ++i)
                #pragma unroll
                for (int j = 0; j < 4; ++j)
                    acc[i][j] = mfma_bf16(af[i][ks], bfr[j][ks], acc[i][j]);
        __builtin_amdgcn_s_setprio(0);
    }

    #pragma unroll
    for (int i = 0; i < 4; ++i) {
        #pragma unroll
        for (int j = 0; j < 4; ++j) {
            #pragma unroll
            for (int r = 0; r < 4; ++r) {
                int row = m0 + wm + i * 16 + half * 4 + r;
                int col = n0 + wn + j * 16 + lr;
                float v = acc[i][j][r];
                if (mode == 1) {
                    outf[(size_t)row * 1024 + col] = v + bias[col];
                } else {
                    int part = col >> 10, cj = col & 1023;
                    int h = cj >> 6, d = cj & 63;
                    int b = row >> 11, n = row & 2047;
                    int bh = b * 16 + h;
                    if (part == 0)   // fold 0.125 * log2(e): attn uses p = 2^s
                        Qs[((size_t)bh * 2048 + n) * 64 + d] = f2bf(v * 0.18033688f);
                    else if (part == 1)
                        Ks[((size_t)bh * 2048 + n) * 64 + d] = f2bf(v);
                    else
                        VTs[((size_t)bh * 64 + d) * 2048 + n] = f2bf(v);
                }
            }
        }
    }
}

// ---------------- flash attention: swapped-QK 32x32, 2 q-blocks/wave --------
// grid (8, 64) XCD-swizzled; block 256 = 4 waves; wave owns 64 q-rows (2x32).
// LDS tiles: 32 rows x 256B, 16-slot XOR swizzle (2-way max aliasing = free).
// p = 2^s directly (scale*log2e folded into Q); row sums via ones-MFMA.
__global__ __launch_bounds__(256, 2) void k_attn(
    const unsigned short* __restrict__ Qs,
    const unsigned short* __restrict__ Ks,
    const unsigned short* __restrict__ VTs,
    unsigned short* __restrict__ attn)   // [8192][1024] bf16
{
    __shared__ unsigned short Kt[2][64 * 64];
    __shared__ unsigned short Vt[2][64 * 64];
    const int tid = threadIdx.x, lane = tid & 63, wave = tid >> 6;

    int lin = blockIdx.y * 8 + blockIdx.x;          // 512 wgs, bijective
    int virt = (lin & 7) * 64 + (lin >> 3);
    int bh = virt >> 3;
    int q0 = (virt & 7) * 256 + wave * 64;

    const int lq = lane & 31;
    const int hi = lane >> 5;
    const bool hib = hi != 0;

    const unsigned short* Kbase = Ks + (size_t)bh * 2048 * 64;
    const unsigned short* Vbase = VTs + (size_t)bh * 64 * 2048;

    u16x8 qf0[4], qf1[4];
    {
        const unsigned short* Qr0 = Qs + ((size_t)bh * 2048 + q0 + lq) * 64;
        const unsigned short* Qr1 = Qr0 + 32 * 64;
        #pragma unroll
        for (int kk = 0; kk < 4; ++kk) {
            qf0[kk] = *(const u16x8*)&Qr0[kk * 16 + hi * 8];
            qf1[kk] = *(const u16x8*)&Qr1[kk * 16 + hi * 8];
        }
    }

    const int srow_in = lane >> 4, sslot = lane & 15;
    auto stage = [&](int buf, int j0) {
        #pragma unroll
        for (int c = 0; c < 2; ++c) {
            int chunk = wave * 2 + c;
            int row = chunk * 4 + srow_in;           // 0..31
            int v = sslot ^ (row & 15);
            int high = v >> 3, dsl = (v & 7) * 8;
            gl_lds16(Kbase + (size_t)(j0 + high * 32 + row) * 64 + dsl, &Kt[buf][chunk * 512]);
            gl_lds16(Vbase + (size_t)(high * 32 + row) * 2048 + j0 + dsl, &Vt[buf][chunk * 512]);
        }
    };

    f32x16 o0[2] = {}, o1[2] = {};
    f32x16 osum0 = {}, osum1 = {};
    const u16x8 onesf = {0x3F80, 0x3F80, 0x3F80, 0x3F80, 0x3F80, 0x3F80, 0x3F80, 0x3F80};

    stage(0, 0);
    __syncthreads();
    int cur = 0;

    for (int t = 0; t < 32; ++t) {
        if (t < 31) stage(cur ^ 1, (t + 1) * 64);

        // ---- QK^T: S^T[j][q] in log2 units, both q-blocks share kf ----
        f32x16 sacc0[2] = {}, sacc1[2] = {};
        __builtin_amdgcn_s_setprio(1);
        #pragma unroll
        for (int jb = 0; jb < 2; ++jb) {
            u16x8 kf[4];
            #pragma unroll
            for (int kk = 0; kk < 4; ++kk) {
                int s = (jb * 8 + kk * 2 + hi) ^ (lq & 15);
                kf[kk] = *(const u16x8*)&Kt[cur][lq * 128 + s * 8];
            }
            #pragma unroll
            for (int kk = 0; kk < 4; ++kk) sacc0[jb] = mfma32(kf[kk], qf0[kk], sacc0[jb]);
            #pragma unroll
            for (int kk = 0; kk < 4; ++kk) sacc1[jb] = mfma32(kf[kk], qf1[kk], sacc1[jb]);
        }
        __builtin_amdgcn_s_setprio(0);

        // ---- p = 2^s, pack to bf16 pairs ----
        unsigned int pk0[16], pk1[16];
        #pragma unroll
        for (int jb = 0; jb < 2; ++jb)
            #pragma unroll
            for (int i = 0; i < 8; ++i) {
                pk0[jb * 8 + i] = cvt_pk_bf16(fexp2(sacc0[jb][2 * i]), fexp2(sacc0[jb][2 * i + 1]));
                pk1[jb * 8 + i] = cvt_pk_bf16(fexp2(sacc1[jb][2 * i]), fexp2(sacc1[jb][2 * i + 1]));
            }

        // ---- PV + ones-MFMA row sums ----
        #pragma unroll
        for (int kk = 0; kk < 4; ++kk) {
            const int base = (kk >> 1) * 8 + (kk & 1) * 4;
            unsigned int a0 = pk0[base + 0], a1 = pk0[base + 1], a2 = pk0[base + 2], a3 = pk0[base + 3];
            unsigned int b0 = pk1[base + 0], b1 = pk1[base + 1], b2 = pk1[base + 2], b3 = pk1[base + 3];
            unsigned int sa0 = __shfl_xor(a0, 32), sa1 = __shfl_xor(a1, 32);
            unsigned int sa2 = __shfl_xor(a2, 32), sa3 = __shfl_xor(a3, 32);
            unsigned int sb0 = __shfl_xor(b0, 32), sb1 = __shfl_xor(b1, 32);
            unsigned int sb2 = __shfl_xor(b2, 32), sb3 = __shfl_xor(b3, 32);
            u32x4 w0, w1;
            w0[0] = hib ? sa2 : a0;  w0[1] = hib ? sa3 : a1;
            w0[2] = hib ? a2 : sa0;  w0[3] = hib ? a3 : sa1;
            w1[0] = hib ? sb2 : b0;  w1[1] = hib ? sb3 : b1;
            w1[2] = hib ? b2 : sb0;  w1[3] = hib ? b3 : sb1;
            u16x8 pa0 = __builtin_bit_cast(u16x8, w0);
            u16x8 pa1 = __builtin_bit_cast(u16x8, w1);
            __builtin_amdgcn_s_setprio(1);
            osum0 = mfma32(pa0, onesf, osum0);
            osum1 = mfma32(pa1, onesf, osum1);
            #pragma unroll
            for (int db = 0; db < 2; ++db) {
                int s = (db * 8 + kk * 2 + hi) ^ (lq & 15);
                u16x8 vf = *(const u16x8*)&Vt[cur][lq * 128 + s * 8];
                o0[db] = mfma32(pa0, vf, o0[db]);
                o1[db] = mfma32(pa1, vf, o1[db]);
            }
            __builtin_amdgcn_s_setprio(0);
        }

        __syncthreads();
        cur ^= 1;
    }

    // ---- epilogue: normalize and store ----
    int b = bh >> 4, h = bh & 15;
    #pragma unroll
    for (int r = 0; r < 16; ++r) {
        int qrow = (r & 3) + 8 * (r >> 2) + 4 * hi;
        float i0 = frcp(osum0[r]);
        float i1 = frcp(osum1[r]);
        size_t ro0 = (size_t)(b * 2048 + q0 + qrow) * 1024 + h * 64;
        size_t ro1 = (size_t)(b * 2048 + q0 + 32 + qrow) * 1024 + h * 64;
        attn[ro0 + lq]      = f2bf(o0[0][r] * i0);
        attn[ro0 + 32 + lq] = f2bf(o0[1][r] * i0);
        attn[ro1 + lq]      = f2bf(o1[0][r] * i1);
        attn[ro1 + 32 + lq] = f2bf(o1[1][r] * i1);
    }
}

extern "C" void kernel_launch(void* const* d_in, const int* in_sizes, int n_in,
                              void* d_out, int out_size, void* d_ws, size_t ws_size,
                              hipStream_t stream) {
    const float* x     = (const float*)d_in[0];
    const float* w_qkv = (const float*)d_in[1];
    const float* w_out = (const float*)d_in[2];
    const float* b_out = (const float*)d_in[3];
    float* out = (float*)d_out;

    char* ws = (char*)d_ws;
    size_t off = 0;
    auto alloc = [&](size_t bytes) -> void* {
        void* p = ws + off;
        off += (bytes + 255) & ~(size_t)255;
        return p;
    };
    unsigned short* xb    = (unsigned short*)alloc(8192ull * 1024 * 2);
    unsigned short* wqkvT = (unsigned short*)alloc(3072ull * 1024 * 2);
    unsigned short* woutT = (unsigned short*)alloc(1024ull * 1024 * 2);
    unsigned short* Qs    = (unsigned short*)alloc(64ull * 2048 * 64 * 2);
    unsigned short* Ks    = (unsigned short*)alloc(64ull * 2048 * 64 * 2);
    unsigned short* VTs   = (unsigned short*)alloc(64ull * 2048 * 64 * 2);
    unsigned short* attn  = (unsigned short*)alloc(8192ull * 1024 * 2);
    if (off > ws_size) return;

    k_cvt<<<2048, 256, 0, stream>>>(x, xb, 8192 * 1024 / 4);
    k_transpose<<<dim3(3072 / 32, 1024 / 32), dim3(32, 8), 0, stream>>>(w_qkv, wqkvT, 1024, 3072);
    k_transpose<<<dim3(1024 / 32, 1024 / 32), dim3(32, 8), 0, stream>>>(w_out, woutT, 1024, 1024);
    k_gemm<<<dim3(3072 / 128, 8192 / 256), 512, 0, stream>>>(xb, wqkvT, nullptr, nullptr, Qs, Ks, VTs, 0);
    k_attn<<<dim3(8, 64), 256, 0, stream>>>(Qs, Ks, VTs, attn);
    k_gemm<<<dim3(1024 / 128, 8192 / 256), 512, 0, stream>>>(attn, woutT, b_out, out, nullptr, nullptr, nullptr, 1);
}

// Round 6
// 216.776 us; speedup vs baseline: 2.8185x; 1.0346x over previous
//
#include <hip/hip_runtime.h>
#include <hip/hip_bf16.h>

// Problem: x[4,2048,1024] f32; w_qkv[1024,3072]; w_out[1024,1024]; b_out[1024]
// out[4,2048,1024] f32.  HEADS=16, DH=64, scale=0.125 (folded with log2e into Q).

typedef __attribute__((ext_vector_type(4))) float f32x4;
typedef __attribute__((ext_vector_type(16))) float f32x16;
typedef __attribute__((ext_vector_type(8))) unsigned short u16x8;
typedef __attribute__((ext_vector_type(4))) unsigned short u16x4;
typedef __attribute__((ext_vector_type(4))) unsigned int u32x4;
typedef __attribute__((ext_vector_type(8))) __bf16 bf16x8;

static __device__ __forceinline__ f32x4 mfma_bf16(u16x8 a, u16x8 b, f32x4 c) {
    return __builtin_amdgcn_mfma_f32_16x16x32_bf16(
        __builtin_bit_cast(bf16x8, a), __builtin_bit_cast(bf16x8, b), c, 0, 0, 0);
}
static __device__ __forceinline__ f32x16 mfma32(u16x8 a, u16x8 b, f32x16 c) {
    return __builtin_amdgcn_mfma_f32_32x32x16_bf16(
        __builtin_bit_cast(bf16x8, a), __builtin_bit_cast(bf16x8, b), c, 0, 0, 0);
}

static __device__ __forceinline__ unsigned short f2bf(float f) {
    unsigned int u = __builtin_bit_cast(unsigned int, f);
    u += 0x7fffu + ((u >> 16) & 1u);   // RNE
    return (unsigned short)(u >> 16);
}
static __device__ __forceinline__ unsigned int cvt_pk_bf16(float a, float b) {
    unsigned int r;
    asm("v_cvt_pk_bf16_f32 %0, %1, %2" : "=v"(r) : "v"(a), "v"(b));
    return r;
}
static __device__ __forceinline__ float fexp2(float x) {   // D = 2^S0
    float r;
    asm("v_exp_f32 %0, %1" : "=v"(r) : "v"(x));
    return r;
}
static __device__ __forceinline__ float frcp(float x) {
    float r;
    asm("v_rcp_f32 %0, %1" : "=v"(r) : "v"(x));
    return r;
}
typedef const __attribute__((address_space(1))) unsigned int* gp1_t;
typedef __attribute__((address_space(3))) unsigned int* lp3_t;
static __device__ __forceinline__ void gl_lds16(const void* g, void* l) {
    __builtin_amdgcn_global_load_lds((gp1_t)g, (lp3_t)l, 16, 0, 0);
}

// ---------------- convert x (f32 -> bf16), vectorized ----------------
__global__ void k_cvt(const float* __restrict__ in, unsigned short* __restrict__ out, int n4) {
    int i = blockIdx.x * blockDim.x + threadIdx.x;
    int stride = gridDim.x * blockDim.x;
    for (; i < n4; i += stride) {
        f32x4 v = ((const f32x4*)in)[i];
        u16x4 o;
        #pragma unroll
        for (int j = 0; j < 4; ++j) o[j] = f2bf(v[j]);
        ((u16x4*)out)[i] = o;
    }
}

// ---------------- transpose f32 [R][C] -> bf16 [C][R] ----------------
__global__ void k_transpose(const float* __restrict__ in, unsigned short* __restrict__ out,
                            int R, int C) {
    __shared__ float tile[32][33];
    int c0 = blockIdx.x * 32, r0 = blockIdx.y * 32;
    int tx = threadIdx.x, ty = threadIdx.y;   // block (32,8)
    #pragma unroll
    for (int i = ty; i < 32; i += 8)
        tile[i][tx] = in[(size_t)(r0 + i) * C + c0 + tx];
    __syncthreads();
    #pragma unroll
    for (int i = ty; i < 32; i += 8)
        out[(size_t)(c0 + i) * R + r0 + tx] = f2bf(tile[tx][i]);
}

// ---------------- GEMM: A[8192][1024]bf16 @ BT[N][1024]bf16 ----------------
// 256x128 tile, BK=64, 8 waves (4M x 2N, 64x64/wave).
// Triple-buffered LDS, 2-tiles-ahead prefetch, 2 phases/K-tile:
//   phase = { 8 ds_read_b128 || 3 gl_lds stage -> bar -> lgkm(0) ->
//             setprio(1) 16 MFMA setprio(0) -> bar }
// vmcnt(6) once per tile (phase 1), never 0 mid-loop.
__global__ __launch_bounds__(512, 1) void k_gemm(
    const unsigned short* __restrict__ A,
    const unsigned short* __restrict__ BT,
    const float* __restrict__ bias,
    float* __restrict__ outf,
    unsigned short* __restrict__ Qs,
    unsigned short* __restrict__ Ks,
    unsigned short* __restrict__ VTs,
    int mode)
{
    __shared__ unsigned short As[3][256 * 64];
    __shared__ unsigned short Bs[3][128 * 64];
    const int K = 1024;
    const int tid = threadIdx.x, lane = tid & 63, wave = tid >> 6;

    // bijective XCD swizzle (nwg % 8 == 0 in both uses)
    int gx = gridDim.x;
    int nwg = gx * gridDim.y;
    int lin = blockIdx.y * gx + blockIdx.x;
    int virt = (lin & 7) * (nwg >> 3) + (lin >> 3);
    int bx = virt % gx, by = virt / gx;
    const int m0 = by * 256, n0 = bx * 128;

    const int wm = (wave >> 1) * 64, wn = (wave & 1) * 64;
    const int lr = lane & 15, half = lane >> 4;
    const int srow = lane >> 3, sslot = lane & 7;

    // stage sub-half h of K-tile t into buffer buf: 2 A-chunks + 1 B-chunk
    // (chunk = 1KB = 8 rows x 8 16B-slots; LDS slot s holds k-chunk s^(row&7))
    auto stage_sub = [&](int buf, int t, int h) {
        int k0 = t * 64;
        #pragma unroll
        for (int r = 0; r < 2; ++r) {
            int chunk = (h * 2 + r) * 8 + wave;       // A chunks 0..31
            int row = chunk * 8 + srow;
            int koff = (sslot ^ (row & 7)) * 8;
            gl_lds16(&A[(size_t)(m0 + row) * K + k0 + koff], &As[buf][chunk * 512]);
        }
        {
            int chunk = h * 8 + wave;                 // B chunks 0..15
            int row = chunk * 8 + srow;
            int koff = (sslot ^ (row & 7)) * 8;
            gl_lds16(&BT[(size_t)(n0 + row) * K + k0 + koff], &Bs[buf][chunk * 512]);
        }
    };

    f32x4 acc[4][4] = {};

    // prologue: tiles 0 and 1 in flight; wait for tile 0 (6 newest = tile 1)
    stage_sub(0, 0, 0); stage_sub(0, 0, 1);
    stage_sub(1, 1, 0); stage_sub(1, 1, 1);
    asm volatile("s_waitcnt vmcnt(6)" ::: "memory");
    __builtin_amdgcn_s_barrier();

    for (int t = 0; t < 16; ++t) {
        const int cur = t % 3, nxt = (t + 2) % 3;
        const bool do_stage = (t + 2) < 16;
        const unsigned short* Ab = As[cur];
        const unsigned short* Bb = Bs[cur];

        #pragma unroll
        for (int ks = 0; ks < 2; ++ks) {
            u16x8 af[4], bfr[4];
            #pragma unroll
            for (int i = 0; i < 4; ++i) {
                int ra = wm + i * 16 + lr;
                af[i] = *(const u16x8*)&Ab[ra * 64 + (((ks * 4 + half) ^ (ra & 7)) * 8)];
                int rb = wn + i * 16 + lr;
                bfr[i] = *(const u16x8*)&Bb[rb * 64 + (((ks * 4 + half) ^ (rb & 7)) * 8)];
            }
            if (do_stage) stage_sub(nxt, t + 2, ks);
            if (ks == 1) {
                // end-of-tile: ensure tile t+1's buffer is ready before next
                // iteration's ds_reads; keep tile t+2's 6 loads in flight.
                if (t < 14)       asm volatile("s_waitcnt vmcnt(6)" ::: "memory");
                else if (t == 14) asm volatile("s_waitcnt vmcnt(0)" ::: "memory");
            }
            __builtin_amdgcn_s_barrier();
            asm volatile("s_waitcnt lgkmcnt(0)" ::: "memory");
            __builtin_amdgcn_sched_barrier(0);
            __builtin_amdgcn_s_setprio(1);
            #pragma unroll
            for (int i = 0; i < 4; ++i)
                #pragma unroll
                for (int j = 0; j < 4; ++j)
                    acc[i][j] = mfma_bf16(af[i], bfr[j], acc[i][j]);
            __builtin_amdgcn_s_setprio(0);
            __builtin_amdgcn_s_barrier();
        }
    }

    #pragma unroll
    for (int i = 0; i < 4; ++i) {
        #pragma unroll
        for (int j = 0; j < 4; ++j) {
            #pragma unroll
            for (int r = 0; r < 4; ++r) {
                int row = m0 + wm + i * 16 + half * 4 + r;
                int col = n0 + wn + j * 16 + lr;
                float v = acc[i][j][r];
                if (mode == 1) {
                    outf[(size_t)row * 1024 + col] = v + bias[col];
                } else {
                    int part = col >> 10, cj = col & 1023;
                    int h = cj >> 6, d = cj & 63;
                    int b = row >> 11, n = row & 2047;
                    int bh = b * 16 + h;
                    if (part == 0)   // fold 0.125 * log2(e): attn uses p = 2^s
                        Qs[((size_t)bh * 2048 + n) * 64 + d] = f2bf(v * 0.18033688f);
                    else if (part == 1)
                        Ks[((size_t)bh * 2048 + n) * 64 + d] = f2bf(v);
                    else
                        VTs[((size_t)bh * 64 + d) * 2048 + n] = f2bf(v);
                }
            }
        }
    }
}

// ---------------- flash attention: swapped-QK 32x32, 2 q-blocks/wave --------
// grid (8, 64) XCD-swizzled; block 256 = 4 waves; wave owns 64 q-rows (2x32).
// LDS tiles: 32 rows x 256B, 16-slot XOR swizzle (2-way max aliasing = free).
// p = 2^s directly (scale*log2e folded into Q); row sums via ones-MFMA.
__global__ __launch_bounds__(256, 2) void k_attn(
    const unsigned short* __restrict__ Qs,
    const unsigned short* __restrict__ Ks,
    const unsigned short* __restrict__ VTs,
    unsigned short* __restrict__ attn)   // [8192][1024] bf16
{
    __shared__ unsigned short Kt[2][64 * 64];
    __shared__ unsigned short Vt[2][64 * 64];
    const int tid = threadIdx.x, lane = tid & 63, wave = tid >> 6;

    int lin = blockIdx.y * 8 + blockIdx.x;          // 512 wgs, bijective
    int virt = (lin & 7) * 64 + (lin >> 3);
    int bh = virt >> 3;
    int q0 = (virt & 7) * 256 + wave * 64;

    const int lq = lane & 31;
    const int hi = lane >> 5;
    const bool hib = hi != 0;

    const unsigned short* Kbase = Ks + (size_t)bh * 2048 * 64;
    const unsigned short* Vbase = VTs + (size_t)bh * 64 * 2048;

    u16x8 qf0[4], qf1[4];
    {
        const unsigned short* Qr0 = Qs + ((size_t)bh * 2048 + q0 + lq) * 64;
        const unsigned short* Qr1 = Qr0 + 32 * 64;
        #pragma unroll
        for (int kk = 0; kk < 4; ++kk) {
            qf0[kk] = *(const u16x8*)&Qr0[kk * 16 + hi * 8];
            qf1[kk] = *(const u16x8*)&Qr1[kk * 16 + hi * 8];
        }
    }

    const int srow_in = lane >> 4, sslot = lane & 15;
    auto stage = [&](int buf, int j0) {
        #pragma unroll
        for (int c = 0; c < 2; ++c) {
            int chunk = wave * 2 + c;
            int row = chunk * 4 + srow_in;           // 0..31
            int v = sslot ^ (row & 15);
            int high = v >> 3, dsl = (v & 7) * 8;
            gl_lds16(Kbase + (size_t)(j0 + high * 32 + row) * 64 + dsl, &Kt[buf][chunk * 512]);
            gl_lds16(Vbase + (size_t)(high * 32 + row) * 2048 + j0 + dsl, &Vt[buf][chunk * 512]);
        }
    };

    f32x16 o0[2] = {}, o1[2] = {};
    f32x16 osum0 = {}, osum1 = {};
    const u16x8 onesf = {0x3F80, 0x3F80, 0x3F80, 0x3F80, 0x3F80, 0x3F80, 0x3F80, 0x3F80};

    stage(0, 0);
    __syncthreads();
    int cur = 0;

    for (int t = 0; t < 32; ++t) {
        if (t < 31) stage(cur ^ 1, (t + 1) * 64);

        // ---- QK^T: S^T[j][q] in log2 units, both q-blocks share kf ----
        f32x16 sacc0[2] = {}, sacc1[2] = {};
        __builtin_amdgcn_s_setprio(1);
        #pragma unroll
        for (int jb = 0; jb < 2; ++jb) {
            u16x8 kf[4];
            #pragma unroll
            for (int kk = 0; kk < 4; ++kk) {
                int s = (jb * 8 + kk * 2 + hi) ^ (lq & 15);
                kf[kk] = *(const u16x8*)&Kt[cur][lq * 128 + s * 8];
            }
            #pragma unroll
            for (int kk = 0; kk < 4; ++kk) sacc0[jb] = mfma32(kf[kk], qf0[kk], sacc0[jb]);
            #pragma unroll
            for (int kk = 0; kk < 4; ++kk) sacc1[jb] = mfma32(kf[kk], qf1[kk], sacc1[jb]);
        }
        __builtin_amdgcn_s_setprio(0);

        // ---- p = 2^s, pack to bf16 pairs ----
        unsigned int pk0[16], pk1[16];
        #pragma unroll
        for (int jb = 0; jb < 2; ++jb)
            #pragma unroll
            for (int i = 0; i < 8; ++i) {
                pk0[jb * 8 + i] = cvt_pk_bf16(fexp2(sacc0[jb][2 * i]), fexp2(sacc0[jb][2 * i + 1]));
                pk1[jb * 8 + i] = cvt_pk_bf16(fexp2(sacc1[jb][2 * i]), fexp2(sacc1[jb][2 * i + 1]));
            }

        // ---- PV + ones-MFMA row sums ----
        #pragma unroll
        for (int kk = 0; kk < 4; ++kk) {
            const int base = (kk >> 1) * 8 + (kk & 1) * 4;
            unsigned int a0 = pk0[base + 0], a1 = pk0[base + 1], a2 = pk0[base + 2], a3 = pk0[base + 3];
            unsigned int b0 = pk1[base + 0], b1 = pk1[base + 1], b2 = pk1[base + 2], b3 = pk1[base + 3];
            unsigned int sa0 = __shfl_xor(a0, 32), sa1 = __shfl_xor(a1, 32);
            unsigned int sa2 = __shfl_xor(a2, 32), sa3 = __shfl_xor(a3, 32);
            unsigned int sb0 = __shfl_xor(b0, 32), sb1 = __shfl_xor(b1, 32);
            unsigned int sb2 = __shfl_xor(b2, 32), sb3 = __shfl_xor(b3, 32);
            u32x4 w0, w1;
            w0[0] = hib ? sa2 : a0;  w0[1] = hib ? sa3 : a1;
            w0[2] = hib ? a2 : sa0;  w0[3] = hib ? a3 : sa1;
            w1[0] = hib ? sb2 : b0;  w1[1] = hib ? sb3 : b1;
            w1[2] = hib ? b2 : sb0;  w1[3] = hib ? b3 : sb1;
            u16x8 pa0 = __builtin_bit_cast(u16x8, w0);
            u16x8 pa1 = __builtin_bit_cast(u16x8, w1);
            __builtin_amdgcn_s_setprio(1);
            osum0 = mfma32(pa0, onesf, osum0);
            osum1 = mfma32(pa1, onesf, osum1);
            #pragma unroll
            for (int db = 0; db < 2; ++db) {
                int s = (db * 8 + kk * 2 + hi) ^ (lq & 15);
                u16x8 vf = *(const u16x8*)&Vt[cur][lq * 128 + s * 8];
                o0[db] = mfma32(pa0, vf, o0[db]);
                o1[db] = mfma32(pa1, vf, o1[db]);
            }
            __builtin_amdgcn_s_setprio(0);
        }

        __syncthreads();
        cur ^= 1;
    }

    // ---- epilogue: normalize and store ----
    int b = bh >> 4, h = bh & 15;
    #pragma unroll
    for (int r = 0; r < 16; ++r) {
        int qrow = (r & 3) + 8 * (r >> 2) + 4 * hi;
        float i0 = frcp(osum0[r]);
        float i1 = frcp(osum1[r]);
        size_t ro0 = (size_t)(b * 2048 + q0 + qrow) * 1024 + h * 64;
        size_t ro1 = (size_t)(b * 2048 + q0 + 32 + qrow) * 1024 + h * 64;
        attn[ro0 + lq]      = f2bf(o0[0][r] * i0);
        attn[ro0 + 32 + lq] = f2bf(o0[1][r] * i0);
        attn[ro1 + lq]      = f2bf(o1[0][r] * i1);
        attn[ro1 + 32 + lq] = f2bf(o1[1][r] * i1);
    }
}

extern "C" void kernel_launch(void* const* d_in, const int* in_sizes, int n_in,
                              void* d_out, int out_size, void* d_ws, size_t ws_size,
                              hipStream_t stream) {
    const float* x     = (const float*)d_in[0];
    const float* w_qkv = (const float*)d_in[1];
    const float* w_out = (const float*)d_in[2];
    const float* b_out = (const float*)d_in[3];
    float* out = (float*)d_out;

    char* ws = (char*)d_ws;
    size_t off = 0;
    auto alloc = [&](size_t bytes) -> void* {
        void* p = ws + off;
        off += (bytes + 255) & ~(size_t)255;
        return p;
    };
    unsigned short* xb    = (unsigned short*)alloc(8192ull * 1024 * 2);
    unsigned short* wqkvT = (unsigned short*)alloc(3072ull * 1024 * 2);
    unsigned short* woutT = (unsigned short*)alloc(1024ull * 1024 * 2);
    unsigned short* Qs    = (unsigned short*)alloc(64ull * 2048 * 64 * 2);
    unsigned short* Ks    = (unsigned short*)alloc(64ull * 2048 * 64 * 2);
    unsigned short* VTs   = (unsigned short*)alloc(64ull * 2048 * 64 * 2);
    unsigned short* attn  = (unsigned short*)alloc(8192ull * 1024 * 2);
    if (off > ws_size) return;

    k_cvt<<<2048, 256, 0, stream>>>(x, xb, 8192 * 1024 / 4);
    k_transpose<<<dim3(3072 / 32, 1024 / 32), dim3(32, 8), 0, stream>>>(w_qkv, wqkvT, 1024, 3072);
    k_transpose<<<dim3(1024 / 32, 1024 / 32), dim3(32, 8), 0, stream>>>(w_out, woutT, 1024, 1024);
    k_gemm<<<dim3(3072 / 128, 8192 / 256), 512, 0, stream>>>(xb, wqkvT, nullptr, nullptr, Qs, Ks, VTs, 0);
    k_attn<<<dim3(8, 64), 256, 0, stream>>>(Qs, Ks, VTs, attn);
    k_gemm<<<dim3(1024 / 128, 8192 / 256), 512, 0, stream>>>(attn, woutT, b_out, out, nullptr, nullptr, nullptr, 1);
}